// Round 2
// baseline (592.068 us; speedup 1.0000x reference)
//
#include <hip/hip_runtime.h>
#include <math.h>

#define N_TOK 16384
#define DM    2048
#define NE    64
#define TOPK  4

#define OFF_TI  0
#define OFF_TS  (N_TOK * TOPK)
#define OFF_SC  (2 * N_TOK * TOPK)
#define OFF_AUX (2 * N_TOK * TOPK + N_TOK * NE)

#define TPB   64              // tokens per block
#define DCH   64              // dims per chunk (16 waves x 4 dims)
#define NCH   (DM / DCH)      // 32 chunks
#define USTR  68              // u LDS row stride (dwords), 16B-aligned rows
#define ESTR  68              // E LDS row stride (dwords)
#define UB    (TPB * USTR)    // 4352 dwords per u buffer
#define EB    (DCH * ESTR)    // 4352 dwords per E buffer
#define EOFF  (3 * UB)        // E region after 3 u buffers

// Block: 1024 threads = 16 waves, 64 tokens, all 64 experts.
// Lane = (t8,e8): tokens t8*8..+7 x experts e8*8..+7 -> acc[8][8] (64 VGPR).
// Wave w owns dims {c*64 + w*4 + 0..3} per chunk -> per chunk per wave only
// 8 u-b128 + 8 E-b128 LDS reads for 256 fmacs (1:16; was 1:3.6 -> LDS-bound).
// 3-deep LDS buffers (global->reg->LDS, load issued 2 chunks ahead).
// Cross-wave dim-partial reduction: ds_add_f32 into bank-swizzled fin[64][68].
__global__ __launch_bounds__(1024, 4) void router_main(
    const float* __restrict__ u, const float* __restrict__ E,
    const float* __restrict__ bias, float* __restrict__ out,
    float* __restrict__ ws)
{
  __shared__ float smem[3 * UB + 3 * EB];   // 26112 dwords = 102 KB

  const int tid  = threadIdx.x;
  const int lane = tid & 63;
  const int wid  = __builtin_amdgcn_readfirstlane(tid >> 6);
  const int t8   = lane >> 3;   // token octet
  const int e8   = lane & 7;    // expert octet
  const int tok0 = blockIdx.x * TPB;

  // ---- staging assignment (shared by u and E): thread -> (row, 16B quad) ----
  const int srow = tid >> 4;    // 0..63: u: token; E: dim-within-chunk
  const int sq   = tid & 15;    // 16B quad within 64-float row
  const float* ugp = u + (size_t)(tok0 + srow) * DM + sq * 4;  // +c*DCH
  const float* egp = E + (size_t)srow * NE + sq * 4;           // +c*DCH*NE
  const int uwp = srow * USTR + sq * 4;                        // +buf*UB
  const int ewp = EOFF + srow * ESTR + sq * 4;                 // +buf*EB

  float acc[8][8];
#pragma unroll
  for (int i = 0; i < 8; ++i)
#pragma unroll
    for (int j = 0; j < 8; ++j) acc[i][j] = 0.f;

  // ---- prologue: fill buffers 0 and 1 ----
  {
    float4 ua = *(const float4*)(ugp);
    float4 ea = *(const float4*)(egp);
    *(float4*)(smem + uwp) = ua;
    *(float4*)(smem + ewp) = ea;
    ua = *(const float4*)(ugp + DCH);
    ea = *(const float4*)(egp + DCH * NE);
    *(float4*)(smem + UB + uwp) = ua;
    *(float4*)(smem + EB + ewp) = ea;
  }
  __syncthreads();

  for (int c = 0; c < NCH; ++c) {
    const int bc  = c % 3;                    // compute buffer
    int bs3 = bc + 2; if (bs3 >= 3) bs3 -= 3; // store buffer (= (c+2)%3)

    float4 ua, ea;
    if (c + 2 < NCH) {                        // issue loads for chunk c+2
      ua = *(const float4*)(ugp + (c + 2) * DCH);
      ea = *(const float4*)(egp + (size_t)(c + 2) * DCH * NE);
    }

    // ---- compute chunk c: wave dims = c*64 + wid*4 + (0..3) ----
    const float* ubs = smem + bc * UB + (t8 * 8) * USTR + wid * 4;
    const float* ebs = smem + EOFF + bc * EB + (wid * 4) * ESTR + e8 * 8;

    float4 er[4][2];
#pragma unroll
    for (int d = 0; d < 4; ++d) {
      er[d][0] = *(const float4*)(ebs + d * ESTR);
      er[d][1] = *(const float4*)(ebs + d * ESTR + 4);
    }
#pragma unroll
    for (int i = 0; i < 8; ++i) {
      float4 uf = *(const float4*)(ubs + i * USTR);
#pragma unroll
      for (int d = 0; d < 4; ++d) {
        const float uv = (d == 0) ? uf.x : (d == 1) ? uf.y : (d == 2) ? uf.z : uf.w;
        acc[i][0] = fmaf(er[d][0].x, uv, acc[i][0]);
        acc[i][1] = fmaf(er[d][0].y, uv, acc[i][1]);
        acc[i][2] = fmaf(er[d][0].z, uv, acc[i][2]);
        acc[i][3] = fmaf(er[d][0].w, uv, acc[i][3]);
        acc[i][4] = fmaf(er[d][1].x, uv, acc[i][4]);
        acc[i][5] = fmaf(er[d][1].y, uv, acc[i][5]);
        acc[i][6] = fmaf(er[d][1].z, uv, acc[i][6]);
        acc[i][7] = fmaf(er[d][1].w, uv, acc[i][7]);
      }
    }

    if (c + 2 < NCH) {                        // land prefetch into free buffer
      *(float4*)(smem + bs3 * UB + uwp) = ua;
      *(float4*)(smem + bs3 * EB + ewp) = ea;
    }
    __syncthreads();
  }

  // ---- reduce 16 per-wave dim-partials into fin[64 tok][68] (aliases smem) ----
  float* fin = smem;
  for (int k = tid; k < UB; k += 1024) fin[k] = 0.f;
  __syncthreads();
#pragma unroll
  for (int i = 0; i < 8; ++i) {
    float* fr = fin + (t8 * 8 + i) * USTR;
#pragma unroll
    for (int j = 0; j < 8; ++j) {
      // column swizzle (low 3 bits XOR t8): spreads banks to 2-way (free)
      atomicAdd(fr + (e8 * 8 + (j ^ t8)), acc[i][j]);
    }
  }
  __syncthreads();

  // ---- epilogue: wave w -> tokens w*4..+3, lane = expert ----
  const float be = bias[lane];
  float asum = 0.f;
#pragma unroll
  for (int tt = 0; tt < 4; ++tt) {
    const int t = wid * 4 + tt;
    const int col = (lane & 56) | ((lane & 7) ^ (t >> 3));
    float x = fin[t * USTR + col] + be;

    float m = x;
#pragma unroll
    for (int off = 32; off > 0; off >>= 1) m = fmaxf(m, __shfl_xor(m, off));
    float p = expf(x - m);
    float s = p;
#pragma unroll
    for (int off = 32; off > 0; off >>= 1) s += __shfl_xor(s, off);
    float sc = p / s;

    out[OFF_SC + (size_t)(tok0 + t) * NE + lane] = sc;
    asum += sc;

    float v = sc;
#pragma unroll
    for (int k = 0; k < TOPK; ++k) {
      float bv = v;
      int   bi = lane;
#pragma unroll
      for (int off = 32; off > 0; off >>= 1) {
        float ov = __shfl_xor(bv, off);
        int   oi = __shfl_xor(bi, off);
        if (ov > bv || (ov == bv && oi < bi)) { bv = ov; bi = oi; }
      }
      if (lane == k) {
        out[OFF_TI + (size_t)(tok0 + t) * TOPK + k] = (float)bi;
        out[OFF_TS + (size_t)(tok0 + t) * TOPK + k] = bv;
      }
      if (lane == bi) v = -INFINITY;
    }
  }
  atomicAdd(&ws[lane], asum);   // per-expert partial for aux loss
}

__global__ void router_aux(const float* __restrict__ ws, float* __restrict__ out)
{
  const int lane = threadIdx.x & 63;
  float m = ws[lane] * (1.0f / N_TOK);
  float v = m * m;
#pragma unroll
  for (int off = 32; off > 0; off >>= 1) v += __shfl_xor(v, off);
  if (lane == 0) out[OFF_AUX] = v * (float)NE;
}

extern "C" void kernel_launch(void* const* d_in, const int* in_sizes, int n_in,
                              void* d_out, int out_size, void* d_ws, size_t ws_size,
                              hipStream_t stream) {
  const float* u    = (const float*)d_in[0];
  const float* E    = (const float*)d_in[1];
  const float* bias = (const float*)d_in[2];
  float* out = (float*)d_out;
  float* ws  = (float*)d_ws;

  hipMemsetAsync(ws, 0, NE * sizeof(float), stream);
  router_main<<<N_TOK / TPB, 1024, 0, stream>>>(u, E, bias, out, ws);
  router_aux<<<1, 64, 0, stream>>>(ws, out);
}

// Round 4
// 315.642 us; speedup vs baseline: 1.8758x; 1.8758x over previous
//
#include <hip/hip_runtime.h>
#include <math.h>

#define N_TOK 16384
#define DM    2048
#define NE    64
#define TOPK  4

#define OFF_TI  0
#define OFF_TS  (N_TOK * TOPK)
#define OFF_SC  (2 * N_TOK * TOPK)
#define OFF_AUX (2 * N_TOK * TOPK + N_TOK * NE)

#define TPB 64               // tokens per block (both paths)

// ---------------- MFMA path ----------------
#define BK    64             // dims per staged chunk
#define NCHK  (DM / BK)      // 32
#define KSTR  72             // u bf16 plane row stride (144B: 8-phase-minimal b128)
#define UPL   (TPB * KSTR)   // 4608 bf16 per plane

#define EH_OFF   1024                      // byte offset of Eh_t in ws
#define ET_ELEMS ((size_t)NE * DM)
#define WS_NEED  (EH_OFF + 4 * ET_ELEMS)   // 525,312 B

typedef short s8v __attribute__((ext_vector_type(8)));   // 8 bf16 = 4 VGPR
typedef float f4v __attribute__((ext_vector_type(4)));

__device__ __forceinline__ unsigned short bf16_rne(float x) {
  unsigned int b = __float_as_uint(x);
  b += 0x7FFFu + ((b >> 16) & 1u);
  return (unsigned short)(b >> 16);
}

// E[2048][64] f32 -> Eh_t/El_t[64 e][2048 k] bf16 (split: E = hi + lo + ~2^-18).
// Runs once per launch, ~5 us; LDS-tile transpose, coalesced IO.
__global__ __launch_bounds__(256) void router_prep(
    const float* __restrict__ E, unsigned short* __restrict__ eh,
    unsigned short* __restrict__ el)
{
  __shared__ float t[32][65];
  const int tid = threadIdx.x;
  const int k0  = blockIdx.x * 32;
#pragma unroll
  for (int i = 0; i < 2; ++i) {
    const int fi = i * 256 + tid;
    const int kk = fi >> 4, ee = (fi & 15) * 4;
    const float4 v = *(const float4*)(E + (size_t)(k0 + kk) * NE + ee);
    t[kk][ee] = v.x; t[kk][ee + 1] = v.y; t[kk][ee + 2] = v.z; t[kk][ee + 3] = v.w;
  }
  __syncthreads();
  const int e = tid >> 2, ks = (tid & 3) * 8;
  unsigned int hw[4], lw[4];
#pragma unroll
  for (int p = 0; p < 4; ++p) {
    unsigned short h[2], l[2];
#pragma unroll
    for (int q = 0; q < 2; ++q) {
      const float x = t[ks + p * 2 + q][e];
      h[q] = bf16_rne(x);
      l[q] = bf16_rne(x - __uint_as_float((unsigned)h[q] << 16));
    }
    hw[p] = (unsigned)h[0] | ((unsigned)h[1] << 16);
    lw[p] = (unsigned)l[0] | ((unsigned)l[1] << 16);
  }
  const size_t o = (size_t)e * DM + k0 + ks;
  *(uint4*)(eh + o) = make_uint4(hw[0], hw[1], hw[2], hw[3]);
  *(uint4*)(el + o) = make_uint4(lw[0], lw[1], lw[2], lw[3]);
}

// 256 thr = 4 waves, 64 tokens. Wave w: token rows w*16..+15 x all 64 experts;
// acc = 4 x f32x4 = 16 VGPR.
// 4-term split MFMA: (uh+ul)*(Eh+El) exactly -> logit err ~2e-6 (f32-ordering
// level; 3-term's dropped ul*El at ~1.7e-5 flipped near-tied topk indices, R3).
// u: f32 global -> regs -> RNE split -> LDS bf16 planes (dbuf, 2-chunk prefetch).
// E-frags: direct global->VGPR b128 (16KB/chunk, L1-hot across 4 waves).
#define LOAD_U(pf, c) do { _Pragma("unroll") \
  for (int i_ = 0; i_ < 4; ++i_) \
    pf[i_] = *(const float4*)(ugp + (size_t)(c) * BK + i_ * 16); } while (0)

#define WRITE_U(pf, base) do { _Pragma("unroll") \
  for (int i_ = 0; i_ < 4; ++i_) { \
    const float4 v_ = pf[i_]; \
    const unsigned short h0_ = bf16_rne(v_.x), h1_ = bf16_rne(v_.y), \
                         h2_ = bf16_rne(v_.z), h3_ = bf16_rne(v_.w); \
    const unsigned short l0_ = bf16_rne(v_.x - __uint_as_float((unsigned)h0_ << 16)); \
    const unsigned short l1_ = bf16_rne(v_.y - __uint_as_float((unsigned)h1_ << 16)); \
    const unsigned short l2_ = bf16_rne(v_.z - __uint_as_float((unsigned)h2_ << 16)); \
    const unsigned short l3_ = bf16_rne(v_.w - __uint_as_float((unsigned)h3_ << 16)); \
    *(uint2*)&sh[(base) + uoff + i_ * 16] = \
      make_uint2((unsigned)h0_ | ((unsigned)h1_ << 16), (unsigned)h2_ | ((unsigned)h3_ << 16)); \
    *(uint2*)&sh[(base) + UPL + uoff + i_ * 16] = \
      make_uint2((unsigned)l0_ | ((unsigned)l1_ << 16), (unsigned)l2_ | ((unsigned)l3_ << 16)); \
  } } while (0)

#define COMPUTE(c, base) do { _Pragma("unroll") \
  for (int ks_ = 0; ks_ < 2; ++ks_) { \
    const s8v ah_ = *(const s8v*)&sh[(base) + a_off + ks_ * 32]; \
    const s8v al_ = *(const s8v*)&sh[(base) + UPL + a_off + ks_ * 32]; \
    _Pragma("unroll") for (int j_ = 0; j_ < 4; ++j_) { \
      const size_t bo_ = bbase + (size_t)j_ * (16 * DM) + (size_t)(c) * BK + ks_ * 32; \
      const s8v bh_ = *(const s8v*)&eh[bo_]; \
      const s8v bl_ = *(const s8v*)&el[bo_]; \
      acc[j_] = __builtin_amdgcn_mfma_f32_16x16x32_bf16(ah_, bh_, acc[j_], 0, 0, 0); \
      acc[j_] = __builtin_amdgcn_mfma_f32_16x16x32_bf16(ah_, bl_, acc[j_], 0, 0, 0); \
      acc[j_] = __builtin_amdgcn_mfma_f32_16x16x32_bf16(al_, bh_, acc[j_], 0, 0, 0); \
      acc[j_] = __builtin_amdgcn_mfma_f32_16x16x32_bf16(al_, bl_, acc[j_], 0, 0, 0); \
    } } } while (0)

__global__ __launch_bounds__(256, 1) void router_main_mfma(
    const float* __restrict__ u, const unsigned short* __restrict__ eh,
    const unsigned short* __restrict__ el, const float* __restrict__ bias,
    float* __restrict__ out, float* __restrict__ ws)
{
  __shared__ __align__(16) unsigned short sh[4 * UPL];   // 36,864 B

  const int tid  = threadIdx.x;
  const int lane = tid & 63;
  const int w    = __builtin_amdgcn_readfirstlane(tid >> 6);
  const int lm   = lane & 15;          // A: token-in-tile / B: expert-in-tile
  const int lk   = lane >> 4;          // k-group (8 bf16 each)
  const int tok0 = blockIdx.x * TPB;

  // u staging map: thread -> (token row, 16B f32 seg); per-instr 64B coalesced
  const int srow = tid >> 2, sseg = tid & 3;
  const float* ugp = u + (size_t)(tok0 + srow) * DM + sseg * 4;
  const int uoff = srow * KSTR + sseg * 4;     // bf16 elems (+i*16)

  // frag addressing: A row=lane&15, k=(lane>>4)*8+j  (B symmetric)
  const int a_off = (w * 16 + lm) * KSTR + lk * 8;
  const size_t bbase = (size_t)lm * DM + lk * 8;

  f4v acc[4];
#pragma unroll
  for (int j = 0; j < 4; ++j) acc[j] = (f4v){0.f, 0.f, 0.f, 0.f};

  float4 pfA[4], pfB[4];
  LOAD_U(pfA, 0);
  LOAD_U(pfB, 1);
  WRITE_U(pfA, 0);
  __syncthreads();

  for (int cc = 0; cc < NCHK; cc += 2) {
    WRITE_U(pfB, 2 * UPL);                       // chunk cc+1 -> buf1
    if (cc + 2 < NCHK) LOAD_U(pfA, cc + 2);
    COMPUTE(cc, 0);
    __syncthreads();
    if (cc + 2 < NCHK) WRITE_U(pfA, 0);          // chunk cc+2 -> buf0
    if (cc + 3 < NCHK) LOAD_U(pfB, cc + 3);
    COMPUTE(cc + 1, 2 * UPL);
    __syncthreads();
  }

  // ---- D frags (col=lane&15 <-> expert, row=(lane>>4)*4+reg <-> token) ----
  float* fin = (float*)sh;
#pragma unroll
  for (int j = 0; j < 4; ++j)
#pragma unroll
    for (int q = 0; q < 4; ++q)
      fin[(w * 16 + lk * 4 + q) * 68 + j * 16 + lm] = acc[j][q];
  __syncthreads();

  // ---- epilogue: wave w -> its 16 tokens, lane = expert (verified R0/R1) ----
  const float be = bias[lane];
  float asum = 0.f;
  for (int tt = 0; tt < 16; ++tt) {
    const int t = w * 16 + tt;
    float x = fin[t * 68 + lane] + be;

    float m = x;
#pragma unroll
    for (int off = 32; off > 0; off >>= 1) m = fmaxf(m, __shfl_xor(m, off));
    float p = expf(x - m);
    float s = p;
#pragma unroll
    for (int off = 32; off > 0; off >>= 1) s += __shfl_xor(s, off);
    float sc = p / s;

    out[OFF_SC + (size_t)(tok0 + t) * NE + lane] = sc;
    asum += sc;

    float v = sc;
#pragma unroll
    for (int k = 0; k < TOPK; ++k) {
      float bv = v;
      int   bi = lane;
#pragma unroll
      for (int off = 32; off > 0; off >>= 1) {
        float ov = __shfl_xor(bv, off);
        int   oi = __shfl_xor(bi, off);
        if (ov > bv || (ov == bv && oi < bi)) { bv = ov; bi = oi; }
      }
      if (lane == k) {
        out[OFF_TI + (size_t)(tok0 + t) * TOPK + k] = (float)bi;
        out[OFF_TS + (size_t)(tok0 + t) * TOPK + k] = bv;
      }
      if (lane == bi) v = -INFINITY;
    }
  }
  atomicAdd(&ws[lane], asum);
}

// ---------------- fallback (ws too small): proven R1 kernel, 240 us ----------------
#define FB_DC   32
#define FB_NCH  (1024 / FB_DC)
#define FB_LSTR 68
#define FB_UB   (TPB * FB_LSTR)
#define FB_EOFF (2 * FB_UB)
#define FB_EB   (2 * FB_DC * NE)

__global__ __launch_bounds__(1024, 4) void router_main_fb(
    const float* __restrict__ u, const float* __restrict__ E,
    const float* __restrict__ bias, float* __restrict__ out,
    float* __restrict__ ws)
{
  __shared__ float smem[FB_EOFF + 2 * FB_EB];

  const int tid  = threadIdx.x;
  const int lane = tid & 63;
  const int wid  = __builtin_amdgcn_readfirstlane(tid >> 6);
  const int eg   = wid & 7;
  const int kh   = wid >> 3;
  const int tok0 = blockIdx.x * TPB;

  const int stok  = tid >> 4;
  const int sdseg = tid & 15;
  const int skh   = sdseg >> 3;
  const int sdsub = (sdseg & 7) * 4;
  const float* sgbase = u + (size_t)(tok0 + stok) * DM + skh * 1024 + sdsub;
  float* swp = smem + stok * FB_LSTR + sdseg * 4;

  const int eq  = tid & 511;
  const int ekh = tid >> 9;
  const float* egbase = E + (size_t)ekh * 1024 * NE + eq * 4;
  float* ewp = smem + FB_EOFF + ekh * (FB_DC * NE) + eq * 4;

  float acc[8];
#pragma unroll
  for (int j = 0; j < 8; ++j) acc[j] = 0.f;

  float4 pf[3];
  pf[0] = *(const float4*)(sgbase + 0 * FB_DC);
  pf[1] = *(const float4*)(sgbase + 1 * FB_DC);
  pf[2] = *(const float4*)(sgbase + 2 * FB_DC);
  float4 epf = *(const float4*)(egbase + 0 * (FB_DC * NE));
  *(float4*)(swp + 0) = pf[0];
  *(float4*)(ewp + 0) = epf;
  epf = *(const float4*)(egbase + 1 * (FB_DC * NE));
  __syncthreads();

  for (int c = 0; c < FB_NCH; ++c) {
    if (c + 1 < FB_NCH) {
      *(float4*)(swp + ((c + 1) & 1) * FB_UB) = pf[(c + 1) % 3];
      *(float4*)(ewp + ((c + 1) & 1) * FB_EB) = epf;
    }
    if (c + 2 < FB_NCH)
      epf = *(const float4*)(egbase + (c + 2) * (FB_DC * NE));
    if (c + 3 < FB_NCH)
      pf[c % 3] = *(const float4*)(sgbase + (c + 3) * FB_DC);

    const float* sb = smem + (c & 1) * FB_UB + lane * FB_LSTR + kh * FB_DC;
    const float* eb = smem + FB_EOFF + (c & 1) * FB_EB + kh * (FB_DC * NE) + eg * 8;
#pragma unroll
    for (int s = 0; s < 8; ++s) {
      float4 uf = *(const float4*)(sb + s * 4);
#pragma unroll
      for (int dd = 0; dd < 4; ++dd) {
        const float* er = eb + (s * 4 + dd) * NE;
        float4 e0 = *(const float4*)(er);
        float4 e1 = *(const float4*)(er + 4);
        const float uv = (&uf.x)[dd];
        acc[0] = fmaf(e0.x, uv, acc[0]);
        acc[1] = fmaf(e0.y, uv, acc[1]);
        acc[2] = fmaf(e0.z, uv, acc[2]);
        acc[3] = fmaf(e0.w, uv, acc[3]);
        acc[4] = fmaf(e1.x, uv, acc[4]);
        acc[5] = fmaf(e1.y, uv, acc[5]);
        acc[6] = fmaf(e1.z, uv, acc[6]);
        acc[7] = fmaf(e1.w, uv, acc[7]);
      }
    }
    __syncthreads();
  }

  float* fin = smem;
  if (kh == 0) {
#pragma unroll
    for (int j = 0; j < 8; ++j) fin[lane * 65 + eg * 8 + j] = acc[j];
  }
  __syncthreads();
  if (kh == 1) {
#pragma unroll
    for (int j = 0; j < 8; ++j) fin[lane * 65 + eg * 8 + j] += acc[j];
  }
  __syncthreads();

  const float be = bias[lane];
  float asum = 0.f;
#pragma unroll
  for (int tt = 0; tt < 4; ++tt) {
    const int t = wid * 4 + tt;
    float x = fin[t * 65 + lane] + be;

    float m = x;
#pragma unroll
    for (int off = 32; off > 0; off >>= 1) m = fmaxf(m, __shfl_xor(m, off));
    float p = expf(x - m);
    float s = p;
#pragma unroll
    for (int off = 32; off > 0; off >>= 1) s += __shfl_xor(s, off);
    float sc = p / s;

    out[OFF_SC + (size_t)(tok0 + t) * NE + lane] = sc;
    asum += sc;

    float v = sc;
#pragma unroll
    for (int k = 0; k < TOPK; ++k) {
      float bv = v;
      int   bi = lane;
#pragma unroll
      for (int off = 32; off > 0; off >>= 1) {
        float ov = __shfl_xor(bv, off);
        int   oi = __shfl_xor(bi, off);
        if (ov > bv || (ov == bv && oi < bi)) { bv = ov; bi = oi; }
      }
      if (lane == k) {
        out[OFF_TI + (size_t)(tok0 + t) * TOPK + k] = (float)bi;
        out[OFF_TS + (size_t)(tok0 + t) * TOPK + k] = bv;
      }
      if (lane == bi) v = -INFINITY;
    }
  }
  atomicAdd(&ws[lane], asum);
}

__global__ void router_aux(const float* __restrict__ ws, float* __restrict__ out)
{
  const int lane = threadIdx.x & 63;
  float m = ws[lane] * (1.0f / N_TOK);
  float v = m * m;
#pragma unroll
  for (int off = 32; off > 0; off >>= 1) v += __shfl_xor(v, off);
  if (lane == 0) out[OFF_AUX] = v * (float)NE;
}

extern "C" void kernel_launch(void* const* d_in, const int* in_sizes, int n_in,
                              void* d_out, int out_size, void* d_ws, size_t ws_size,
                              hipStream_t stream) {
  const float* u    = (const float*)d_in[0];
  const float* E    = (const float*)d_in[1];
  const float* bias = (const float*)d_in[2];
  float* out = (float*)d_out;
  float* ws  = (float*)d_ws;

  hipMemsetAsync(ws, 0, NE * sizeof(float), stream);
  if (ws_size >= WS_NEED) {
    unsigned short* eh = (unsigned short*)((char*)ws + EH_OFF);
    unsigned short* el = eh + ET_ELEMS;
    router_prep<<<DM / 32, 256, 0, stream>>>(E, eh, el);
    router_main_mfma<<<N_TOK / TPB, 256, 0, stream>>>(u, eh, el, bias, out, ws);
  } else {
    router_main_fb<<<N_TOK / TPB, 1024, 0, stream>>>(u, E, bias, out, ws);
  }
  router_aux<<<1, 64, 0, stream>>>(ws, out);
}